// Round 1
// 131.792 us; speedup vs baseline: 1.0203x; 1.0203x over previous
//
#include <hip/hip_runtime.h>

// Neural stack, closed form. Round 7: split prefix-scan precompute into its
// own tiny kernel (packed transposed G/H/d table in a device global), drop
// all LDS + barriers from the main kernel, 4-deep MLP in the v-row gather,
// and 2x grid oversubscription (4 rows/wave) for tail balance.
//
// s_j^(t) = relu(d_j - relu(max_{j<tau<=t} G_tau - H_j)),
//   G_tau = U_tau - Dp_{tau-1}, H_j = U_j - Dp_j  (prefix sums of u, d).
// Per row t (p = t - j): M = exclusive prefix-MAX of G, C = exclusive
// prefix-SUM of s, coeff = min(s, relu(1-C)); exactly 0 once C >= 1.

#define TT 512
#define BB 128
#define EE 256

typedef float v4f __attribute__((ext_vector_type(4)));

// packed per-(b,t): {G, H, d, 0} — one coalesced dwordx4 per lane per chunk
__device__ v4f g_GHD[BB * TT];

template <int CTRL, int RM>
__device__ __forceinline__ float dppmov(float o, float s) {
  return __int_as_float(__builtin_amdgcn_update_dpp(
      __float_as_int(o), __float_as_int(s), CTRL, RM, 0xf, false));
}

__device__ __forceinline__ float readlanef(float v, int l) {
  return __int_as_float(__builtin_amdgcn_readlane(__float_as_int(v), l));
}

// wave64 inclusive max-scan (identity -inf)
__device__ __forceinline__ float scan_max64(float v) {
  const float NI = -__builtin_inff();
  v = fmaxf(v, dppmov<0x111, 0xf>(NI, v));   // row_shr:1
  v = fmaxf(v, dppmov<0x112, 0xf>(NI, v));   // row_shr:2
  v = fmaxf(v, dppmov<0x114, 0xf>(NI, v));   // row_shr:4
  v = fmaxf(v, dppmov<0x118, 0xf>(NI, v));   // row_shr:8
  v = fmaxf(v, dppmov<0x142, 0xa>(NI, v));   // row_bcast:15 -> rows 1,3
  v = fmaxf(v, dppmov<0x143, 0xc>(NI, v));   // row_bcast:31 -> rows 2,3
  return v;
}

// wave64 inclusive sum-scan (identity 0)
__device__ __forceinline__ float scan_add64(float v) {
  v += dppmov<0x111, 0xf>(0.f, v);
  v += dppmov<0x112, 0xf>(0.f, v);
  v += dppmov<0x114, 0xf>(0.f, v);
  v += dppmov<0x118, 0xf>(0.f, v);
  v += dppmov<0x142, 0xa>(0.f, v);
  v += dppmov<0x143, 0xc>(0.f, v);
  return v;
}

// whole-wave shift right by 1 (lane0 <- carry)
__device__ __forceinline__ float wshr1(float carry, float v) {
  return __int_as_float(__builtin_amdgcn_update_dpp(
      __float_as_int(carry), __float_as_int(v), 0x138, 0xf, 0xf, false));
}

// ---------------------------------------------------------------------------
// Kernel A: per-batch f64 prefix sums of u,d -> packed (G,H,d) table.
// One wave per b. All 8 chunk-scans advance in lockstep (ILP across chunks),
// then an 8-step serial carry fixup + write. ~1-2 us total.
// ---------------------------------------------------------------------------
__global__ __launch_bounds__(64) void precompute_kernel(
    const float* __restrict__ u, const float* __restrict__ d) {
  const int b = blockIdx.x;
  const int lane = threadIdx.x;

  double su[8], sv[8];
  float dv[8];
#pragma unroll
  for (int c = 0; c < 8; ++c) {
    const int t = c * 64 + lane;
    const float uv = u[t * BB + b];
    const float dd = d[t * BB + b];
    dv[c] = dd;
    su[c] = (double)uv;
    sv[c] = (double)dd;
  }
#pragma unroll
  for (int o = 1; o < 64; o <<= 1) {
#pragma unroll
    for (int c = 0; c < 8; ++c) {
      const double yu = __shfl_up(su[c], o);
      const double yv = __shfl_up(sv[c], o);
      if (lane >= o) { su[c] += yu; sv[c] += yv; }
    }
  }
  double oU = 0.0, oD = 0.0;
#pragma unroll
  for (int c = 0; c < 8; ++c) {
    const double U = oU + su[c];
    const double D = oD + sv[c];
    v4f w;
    w.x = (float)(U - (D - (double)dv[c]));  // G_t = U_t - Dp_{t-1}
    w.y = (float)(U - D);                    // H_t = U_t - Dp_t
    w.z = dv[c];
    w.w = 0.f;
    g_GHD[b * TT + c * 64 + lane] = w;
    oU += __shfl(su[c], 63);
    oD += __shfl(sv[c], 63);
  }
}

// ---------------------------------------------------------------------------
// Kernel B: the walks. No LDS, no barriers — 4 independent waves/block.
// Wave sw (0..127) of batch b handles rows t = sw + 128*r, r in [0,4).
// Grid = 4096 blocks = 2x device capacity -> backfill absorbs the
// data-dependent early-break imbalance.
// ---------------------------------------------------------------------------
__launch_bounds__(256)
__global__ void stack_kernel(const float* __restrict__ v,
                             float* __restrict__ out) {
  const int bid = blockIdx.x;
  const int b = bid & (BB - 1);
  const int q = bid >> 7;                 // 0..31
  const int wave = threadIdx.x >> 6;
  const int lane = threadIdx.x & 63;
  const int sw = (q << 2) | wave;         // 0..127

  const v4f* __restrict__ GHD = g_GHD + b * TT;
  const v4f* __restrict__ vb = (const v4f*)(v + b * EE);
  // v row stride in float4s: BB*EE/4 = 8192 = 1<<13
  const float NI = -__builtin_inff();

  for (int r = 0; r < 4; ++r) {
    const int t = sw + 128 * r;
    v4f acc = {0.f, 0.f, 0.f, 0.f};
    float Ccarry = 0.f;
    float Mcarry = NI;

    for (int base = 0; base <= t; base += 64) {
      const int p = base + lane;          // position from top (p=0 -> j=t)
      const int j = t - p;
      const int jc = j < 0 ? 0 : j;
      const bool in = (p <= t);
      const v4f gh = GHD[jc];             // one dwordx4, coalesced (reversed)
      const float Gv = in ? gh.x : NI;
      const float Hv = in ? gh.y : 0.f;
      const float dvv = in ? gh.z : 0.f;

      const float gmax = scan_max64(Gv);                     // incl max of G
      const float Mex = fmaxf(wshr1(Mcarry, gmax), Mcarry);  // excl + carry

      const float s = fmaxf(dvv - fmaxf(Mex - Hv, 0.f), 0.f);

      const float csum = scan_add64(s);                      // incl sum of s
      const float Cex = wshr1(0.f, csum) + Ccarry;           // excl + carry

      const float coeff = fminf(s, fmaxf(1.f - Cex, 0.f));

      unsigned long long m = __ballot(coeff > 0.f);
      while (m) {
        // extract up to 4 nonzero lanes; unused slots alias slot 0 with a
        // zero coefficient -> branch-free 4-deep load pipeline.
        const int l0 = __ffsll(m) - 1; m &= m - 1;
        int k1 = l0, k2 = l0, k3 = l0;
        float f1 = 0.f, f2 = 0.f, f3 = 0.f;
        if (m) { k1 = __ffsll(m) - 1; m &= m - 1; f1 = 1.f; }
        if (m) { k2 = __ffsll(m) - 1; m &= m - 1; f2 = 1.f; }
        if (m) { k3 = __ffsll(m) - 1; m &= m - 1; f3 = 1.f; }

        const float c0 = readlanef(coeff, l0);
        const float c1 = f1 * readlanef(coeff, k1);
        const float c2 = f2 * readlanef(coeff, k2);
        const float c3 = f3 * readlanef(coeff, k3);

        const int o0 = ((t - base - l0) << 13) + lane;
        const int o1 = ((t - base - k1) << 13) + lane;
        const int o2 = ((t - base - k2) << 13) + lane;
        const int o3 = ((t - base - k3) << 13) + lane;

        const v4f y0 = vb[o0];
        const v4f y1 = vb[o1];
        const v4f y2 = vb[o2];
        const v4f y3 = vb[o3];

        acc += c0 * y0;
        acc += c1 * y1;
        acc += c2 * y2;
        acc += c3 * y3;
      }

      Ccarry = Ccarry + readlanef(csum, 63);
      Mcarry = fmaxf(Mcarry, readlanef(gmax, 63));
      if (Ccarry >= 1.f) break;           // all deeper coeffs exactly 0
    }

    // write-once output: nontemporal to keep v/GHD hot in L2
    v4f* op = (v4f*)(out + ((size_t)t * BB + b) * EE);
    __builtin_nontemporal_store(acc, op + lane);
  }
}

extern "C" void kernel_launch(void* const* d_in, const int* in_sizes, int n_in,
                              void* d_out, int out_size, void* d_ws,
                              size_t ws_size, hipStream_t stream) {
  const float* v = (const float*)d_in[0];
  const float* u = (const float*)d_in[1];
  const float* dd = (const float*)d_in[2];
  float* out = (float*)d_out;
  (void)in_sizes; (void)n_in; (void)out_size; (void)d_ws; (void)ws_size;

  hipLaunchKernelGGL(precompute_kernel, dim3(BB), dim3(64), 0, stream, u, dd);
  hipLaunchKernelGGL(stack_kernel, dim3(32 * BB), dim3(256), 0, stream,
                     v, out);
}